// Round 12
// baseline (87.271 us; speedup 1.0000x reference)
//
#include <hip/hip_runtime.h>
#include <hip/hip_bf16.h>

#define NSP 2304   // 48*48 spatial
#define NB  4      // batch

typedef unsigned short u16;
typedef __attribute__((ext_vector_type(8))) short short8;
typedef __attribute__((ext_vector_type(4))) float f32x4;
typedef __attribute__((ext_vector_type(4))) unsigned short u16x4;

// scale * log2(e), folded into Q at QKV-GEMM epilogue: softmax p = exp2(S)
#define K1S 0.25508040852656425f

static __device__ inline u16 f2bf(float f) {
  return __builtin_bit_cast(unsigned short, __float2bfloat16(f));
}
// packed f32x2 -> bf16x2 (RNE), single VALU inst; lo16 = cvt(a), hi16 = cvt(b)
static __device__ inline unsigned cvtpk(float a, float b) {
  unsigned r;
  asm("v_cvt_pk_bf16_f32 %0, %1, %2" : "=v"(r) : "v"(a), "v"(b));
  return r;
}

// ---------------------------------------------------------------------------
// prep 1: w_qkv (768*256) and w_out (256*256) fp32 -> bf16, one region.
// ---------------------------------------------------------------------------
__global__ __launch_bounds__(256) void convert_w(
    const float* __restrict__ wq, const float* __restrict__ wo,
    u16* __restrict__ dst) {
  int i = (blockIdx.x * 256 + threadIdx.x) * 4;
  float4 v;
  if (i < 196608) v = *(const float4*)(wq + i);
  else            v = *(const float4*)(wo + (i - 196608));
  u16x4 p = {f2bf(v.x), f2bf(v.y), f2bf(v.z), f2bf(v.w)};
  *(u16x4*)(dst + i) = p;
}

// ---------------------------------------------------------------------------
// prep 2: x fp32 [b][256][2304] -> xT bf16 [b][2304][256]
// ---------------------------------------------------------------------------
__global__ __launch_bounds__(256) void transpose_x(
    const float* __restrict__ x, u16* __restrict__ xT) {
  __shared__ float tile[32][33];
  const int t = threadIdx.x;
  const int n0 = blockIdx.x * 32, c0 = blockIdx.y * 32, b = blockIdx.z;
  const float* xb = x + ((size_t)b * 256 + c0) * NSP + n0;
#pragma unroll
  for (int e = t; e < 1024; e += 256) {
    int cc = e >> 5, nn = e & 31;
    tile[cc][nn] = xb[(size_t)cc * NSP + nn];
  }
  __syncthreads();
  u16* xTb = xT + ((size_t)b * NSP + n0) * 256 + c0;
#pragma unroll
  for (int e = t; e < 1024; e += 256) {
    int nn = e >> 5, cc = e & 31;
    xTb[(size_t)nn * 256 + cc] = f2bf(tile[cc][nn]);
  }
}

// ---------------------------------------------------------------------------
// bf16 MFMA GEMM (LDS-staged): D = A (Mx256) * B[b](Nx256)^T
// 64x64 tile, 4 waves (2x2 of 32x32), whole K=256 staged once.
// EPI 0: rows <256 q (pre-scaled K1S), 256..511 k -> qkT[b][n][512] bf16;
//        rows >=512 v -> vbuf[b][256][2304] bf16.
// EPI 1: fp32 out + bias.
// ---------------------------------------------------------------------------
template <int EPI>
__global__ __launch_bounds__(256) void gemm_mfma(
    const u16* __restrict__ A, const u16* __restrict__ B,
    u16* __restrict__ qkT, u16* __restrict__ vbuf,
    float* __restrict__ outf, const float* __restrict__ bias, int N) {
  __shared__ u16 As[64][264];
  __shared__ u16 Bs[64][264];
  const int t = threadIdx.x, lane = t & 63, wid = t >> 6;
  const int lo = lane & 15, g = lane >> 4;
  const int wr = wid >> 1, wc = wid & 1;
  const int row0 = blockIdx.y * 64, col0 = blockIdx.x * 64, b = blockIdx.z;

  const int sr = t >> 2, c4 = t & 3;
  const u16* Arow = A + (size_t)(row0 + sr) * 256;
  const u16* Brow = B + ((size_t)b * N + col0 + sr) * 256;
#pragma unroll
  for (int i = 0; i < 8; ++i) {
    int col = (c4 + 4 * i) * 8;
    *(uint4*)&As[sr][col] = *(const uint4*)&Arow[col];
    *(uint4*)&Bs[sr][col] = *(const uint4*)&Brow[col];
  }
  __syncthreads();

  f32x4 acc[2][2];
#pragma unroll
  for (int i = 0; i < 2; ++i)
#pragma unroll
    for (int j = 0; j < 2; ++j) acc[i][j] = (f32x4){0, 0, 0, 0};

  const int ar0 = wr * 32 + lo, br0 = wc * 32 + lo;
#pragma unroll
  for (int kk = 0; kk < 8; ++kk) {
    int kc = kk * 32 + g * 8;
    short8 a0 = *(const short8*)&As[ar0][kc];
    short8 a1 = *(const short8*)&As[ar0 + 16][kc];
    short8 b0 = *(const short8*)&Bs[br0][kc];
    short8 b1 = *(const short8*)&Bs[br0 + 16][kc];
    acc[0][0] = __builtin_amdgcn_mfma_f32_16x16x32_bf16(a0, b0, acc[0][0], 0, 0, 0);
    acc[0][1] = __builtin_amdgcn_mfma_f32_16x16x32_bf16(a0, b1, acc[0][1], 0, 0, 0);
    acc[1][0] = __builtin_amdgcn_mfma_f32_16x16x32_bf16(a1, b0, acc[1][0], 0, 0, 0);
    acc[1][1] = __builtin_amdgcn_mfma_f32_16x16x32_bf16(a1, b1, acc[1][1], 0, 0, 0);
  }

  const float qs = (EPI == 0 && row0 < 256) ? K1S : 1.0f;
#pragma unroll
  for (int m2 = 0; m2 < 2; ++m2)
#pragma unroll
    for (int n2 = 0; n2 < 2; ++n2) {
      int m = row0 + wr * 32 + m2 * 16 + g * 4;
      int n = col0 + wc * 32 + n2 * 16 + lo;
      if constexpr (EPI == 0) {
        if (row0 < 512) {  // q,k -> transposed qkT[b][n][m..m+3]
          u16x4 pk = {f2bf(acc[m2][n2][0] * qs), f2bf(acc[m2][n2][1] * qs),
                      f2bf(acc[m2][n2][2] * qs), f2bf(acc[m2][n2][3] * qs)};
          *(u16x4*)(qkT + ((size_t)b * NSP + n) * 512 + m) = pk;
        } else {           // v -> natural vbuf[b][m-512][n]
#pragma unroll
          for (int r = 0; r < 4; ++r)
            vbuf[((size_t)b * 256 + (m - 512 + r)) * NSP + n] =
                f2bf(acc[m2][n2][r]);
        }
      } else {
#pragma unroll
        for (int r = 0; r < 4; ++r)
          outf[((size_t)b * 256 + m + r) * NSP + n] =
              acc[m2][n2][r] + bias[m + r];
      }
    }
}

// ---------------------------------------------------------------------------
// MFMA flash attention: issue-optimized body + XOR-swizzled single-buffer LDS.
// 2-wave 128-thr blocks, 48 q/wave (3 Q-frags), KVBLK=128 (18 strips).
// Grid 768 = 3 blocks/CU, all resident (LDS 24.0 KB -> 6 blocks/CU cap),
// XCD-swizzled (h = blockIdx%8). LDS index swizzle: idx ^= (row&7)<<3
// (16B-granule XOR, T2) -> K/V frag reads and staging writes <=2-way.
// P in-register (sigma trick); V stored sigma-PERMUTED so each V-fragment is
// one b128. Row-sum l via ones-MFMA. setprio(1) around MFMA clusters.
// Strip: [prefetch issue][compute on buf][bar][LDS write][bar].
// ---------------------------------------------------------------------------
#define KIDX(r, c) ((((r) * 64) + (c)) ^ (((r) & 7) << 3))
#define VIDX(r, c) ((((r) * 128) + (c)) ^ (((r) & 7) << 3))

__global__ __launch_bounds__(128, 2) void attn_mfma(
    const u16* __restrict__ qkT, const u16* __restrict__ vbuf,
    u16* __restrict__ attnoT) {
  const int jb = blockIdx.x;
  const int h = jb & 7;
  const int qq = jb >> 3;
  const int it = qq % 24;
  const int b  = qq / 24;
  const int t = threadIdx.x, lane = t & 63, w = t >> 6;
  const int lo = lane & 15, g = lane >> 4;
  const int i0 = it * 96;

  const u16* qkTb = qkT + (size_t)b * NSP * 512;
  const u16* vb   = vbuf + ((size_t)b * 256 + h * 32) * NSP;
  u16* ob = attnoT + ((size_t)b * NSP + i0) * 256 + h * 32;

  __shared__ u16 Kt[128 * 64];   // [key j][d], swizzled via KIDX
  __shared__ u16 Vs[32 * 128];   // [d][perm j], swizzled via VIDX

  // three Q fragments: queries i0 + w*48 + qh*16 + lo (pre-scaled by K1S)
  short8 qf[3];
#pragma unroll
  for (int qh = 0; qh < 3; ++qh)
    qf[qh] = *(const short8*)(qkTb +
              (size_t)(i0 + w * 48 + qh * 16 + lo) * 512 + h * 32 + g * 8);

  // staging (128 thr, 128-key strips):
  // K: thread t -> rows kr+32i (i=0..3), 16B at d-chunk kp.
  // V: thread t -> rows vr+8i (i=0..3), 16B at j-part vjp, written PERMUTED:
  //    col j=(16b1+4gg+rr) within 32-block -> 8gg+4b1+rr, so lane (lo,g)'s
  //    sigma fragment is one contiguous 16B read.
  const int kr = t >> 2, kp = (t & 3) * 8;
  const int vr = t >> 4, vjp = (t & 15) * 8;
  const int pc0 = (vjp & ~31) | (((vjp >> 2) & 3) << 3) | (((vjp >> 4) & 1) << 2);
  const u16* ksrc = qkTb + 256 + h * 32 + kp;            // + (j0+row)*512
  const u16* vsrc = vb + (size_t)vr * NSP + vjp;         // + 8i*NSP + j0

  uint4 kv[4], vv[4];
#pragma unroll
  for (int i = 0; i < 4; ++i) {
    kv[i] = *(const uint4*)(ksrc + (size_t)(kr + 32 * i) * 512);
    vv[i] = *(const uint4*)(vsrc + (size_t)(8 * i) * NSP);
  }
#pragma unroll
  for (int i = 0; i < 4; ++i) {
    *(uint4*)&Kt[KIDX(kr + 32 * i, kp)] = kv[i];
    *(uint2*)&Vs[VIDX(vr + 8 * i, pc0)]     = make_uint2(vv[i].x, vv[i].y);
    *(uint2*)&Vs[VIDX(vr + 8 * i, pc0 + 8)] = make_uint2(vv[i].z, vv[i].w);
  }
  __syncthreads();

  short8 ones;
#pragma unroll
  for (int e = 0; e < 8; ++e) ones[e] = (short)0x3F80;  // bf16 1.0

  f32x4 a0[3], a1[3], al[3];
#pragma unroll
  for (int qh = 0; qh < 3; ++qh) {
    a0[qh] = (f32x4){0, 0, 0, 0};
    a1[qh] = (f32x4){0, 0, 0, 0};
    al[qh] = (f32x4){0, 0, 0, 0};
  }

  for (int s = 0; s < 18; ++s) {
    if (s + 1 < 18) {  // issue next strip's loads early (hide under compute)
      const int j0n = (s + 1) * 128;
#pragma unroll
      for (int i = 0; i < 4; ++i) {
        kv[i] = *(const uint4*)(ksrc + (size_t)(j0n + kr + 32 * i) * 512);
        vv[i] = *(const uint4*)(vsrc + j0n + (size_t)(8 * i) * NSP);
      }
    }

#pragma unroll
    for (int h2 = 0; h2 < 2; ++h2) {
      // K fragments (shared by all 3 q-frags)
      short8 kf0 = *(const short8*)&Kt[KIDX(h2 * 64 + lo, g * 8)];
      short8 kf1 = *(const short8*)&Kt[KIDX(h2 * 64 + 16 + lo, g * 8)];
      short8 kf2 = *(const short8*)&Kt[KIDX(h2 * 64 + 32 + lo, g * 8)];
      short8 kf3 = *(const short8*)&Kt[KIDX(h2 * 64 + 48 + lo, g * 8)];
      // V fragments (single b128 each, permuted layout; shared by all qh)
      short8 vf00 = *(const short8*)&Vs[VIDX(lo, h2 * 64 + 8 * g)];
      short8 vf01 = *(const short8*)&Vs[VIDX(lo, h2 * 64 + 32 + 8 * g)];
      short8 vf10 = *(const short8*)&Vs[VIDX(16 + lo, h2 * 64 + 8 * g)];
      short8 vf11 = *(const short8*)&Vs[VIDX(16 + lo, h2 * 64 + 32 + 8 * g)];

#pragma unroll
      for (int qh = 0; qh < 3; ++qh) {
        __builtin_amdgcn_s_setprio(1);
        f32x4 sv0 = __builtin_amdgcn_mfma_f32_16x16x32_bf16(kf0, qf[qh], (f32x4){0,0,0,0}, 0, 0, 0);
        f32x4 sv1 = __builtin_amdgcn_mfma_f32_16x16x32_bf16(kf1, qf[qh], (f32x4){0,0,0,0}, 0, 0, 0);
        f32x4 sv2 = __builtin_amdgcn_mfma_f32_16x16x32_bf16(kf2, qf[qh], (f32x4){0,0,0,0}, 0, 0, 0);
        f32x4 sv3 = __builtin_amdgcn_mfma_f32_16x16x32_bf16(kf3, qf[qh], (f32x4){0,0,0,0}, 0, 0, 0);
        __builtin_amdgcn_s_setprio(0);

        f32x4 e0, e1, e2, e3;
#pragma unroll
        for (int r = 0; r < 4; ++r) {
          e0[r] = __builtin_amdgcn_exp2f(sv0[r]);
          e1[r] = __builtin_amdgcn_exp2f(sv1[r]);
          e2[r] = __builtin_amdgcn_exp2f(sv2[r]);
          e3[r] = __builtin_amdgcn_exp2f(sv3[r]);
        }
        uint4 P0 = {cvtpk(e0[0], e0[1]), cvtpk(e0[2], e0[3]),
                    cvtpk(e1[0], e1[1]), cvtpk(e1[2], e1[3])};
        uint4 P1 = {cvtpk(e2[0], e2[1]), cvtpk(e2[2], e2[3]),
                    cvtpk(e3[0], e3[1]), cvtpk(e3[2], e3[3])};
        short8 pf0 = __builtin_bit_cast(short8, P0);
        short8 pf1 = __builtin_bit_cast(short8, P1);

        __builtin_amdgcn_s_setprio(1);
        a0[qh] = __builtin_amdgcn_mfma_f32_16x16x32_bf16(pf0, vf00, a0[qh], 0, 0, 0);
        a1[qh] = __builtin_amdgcn_mfma_f32_16x16x32_bf16(pf0, vf10, a1[qh], 0, 0, 0);
        al[qh] = __builtin_amdgcn_mfma_f32_16x16x32_bf16(pf0, ones, al[qh], 0, 0, 0);
        a0[qh] = __builtin_amdgcn_mfma_f32_16x16x32_bf16(pf1, vf01, a0[qh], 0, 0, 0);
        a1[qh] = __builtin_amdgcn_mfma_f32_16x16x32_bf16(pf1, vf11, a1[qh], 0, 0, 0);
        al[qh] = __builtin_amdgcn_mfma_f32_16x16x32_bf16(pf1, ones, al[qh], 0, 0, 0);
        __builtin_amdgcn_s_setprio(0);
      }
    }

    if (s + 1 < 18) {  // single-buffer refill: read-done bar, write, vis bar
      __syncthreads();
#pragma unroll
      for (int i = 0; i < 4; ++i) {
        *(uint4*)&Kt[KIDX(kr + 32 * i, kp)] = kv[i];
        *(uint2*)&Vs[VIDX(vr + 8 * i, pc0)]     = make_uint2(vv[i].x, vv[i].y);
        *(uint2*)&Vs[VIDX(vr + 8 * i, pc0 + 8)] = make_uint2(vv[i].z, vv[i].w);
      }
      __syncthreads();
    }
  }

  // ---- normalize + bf16 store to attnoT[n][c] ----
#pragma unroll
  for (int qh = 0; qh < 3; ++qh)
#pragma unroll
    for (int r = 0; r < 4; ++r) {
      float inv = 1.0f / al[qh][r];
      int row = w * 48 + qh * 16 + g * 4 + r;
      ob[(size_t)row * 256 + lo]      = f2bf(a0[qh][r] * inv);
      ob[(size_t)row * 256 + 16 + lo] = f2bf(a1[qh][r] * inv);
    }
}

// ---------------------------------------------------------------------------
extern "C" void kernel_launch(void* const* d_in, const int* in_sizes, int n_in,
                              void* d_out, int out_size, void* d_ws, size_t ws_size,
                              hipStream_t stream) {
  const float* x     = (const float*)d_in[0];  // [4][256][48][48]
  const float* w_qkv = (const float*)d_in[1];  // [768][256]
  const float* w_out = (const float*)d_in[2];  // [256][256]
  const float* b_out = (const float*)d_in[3];  // [256]
  float* out = (float*)d_out;                  // [4][256][2304]

  u16* wbf    = (u16*)d_ws;                    // wqkv 196608 then wout 65536
  u16* xT     = wbf + 262144;                  // [4][2304][256]
  u16* qkT    = xT + (size_t)NB * NSP * 256;   // [4][2304][512]
  u16* vbuf   = qkT + (size_t)NB * NSP * 512;  // [4][256][2304]
  u16* attnoT = vbuf + (size_t)NB * 256 * NSP; // [4][2304][256]

  dim3 blk(256);
  convert_w<<<256, blk, 0, stream>>>(w_qkv, w_out, wbf);
  transpose_x<<<dim3(NSP / 32, 8, NB), blk, 0, stream>>>(x, xT);
  gemm_mfma<0><<<dim3(NSP / 64, 12, NB), blk, 0, stream>>>(
      wbf, xT, qkT, vbuf, nullptr, nullptr, NSP);
  attn_mfma<<<dim3(768), dim3(128), 0, stream>>>(qkT, vbuf, attnoT);
  gemm_mfma<1><<<dim3(NSP / 64, 4, NB), blk, 0, stream>>>(
      wbf + 196608, attnoT, nullptr, nullptr, out, b_out, NSP);
}

// Round 13
// 84.054 us; speedup vs baseline: 1.0383x; 1.0383x over previous
//
#include <hip/hip_runtime.h>
#include <hip/hip_bf16.h>

#define NSP 2304   // 48*48 spatial
#define NB  4      // batch

typedef unsigned short u16;
typedef __attribute__((ext_vector_type(8))) short short8;
typedef __attribute__((ext_vector_type(4))) short short4v;
typedef __attribute__((ext_vector_type(4))) float f32x4;
typedef __attribute__((ext_vector_type(4))) unsigned short u16x4;

// scale * log2(e), folded into Q at QKV-GEMM epilogue: softmax p = exp2(S)
#define K1S 0.25508040852656425f

static __device__ inline u16 f2bf(float f) {
  return __builtin_bit_cast(unsigned short, __float2bfloat16(f));
}
// packed f32x2 -> bf16x2 (RNE), single VALU inst; lo16 = cvt(a), hi16 = cvt(b)
static __device__ inline unsigned cvtpk(float a, float b) {
  unsigned r;
  asm("v_cvt_pk_bf16_f32 %0, %1, %2" : "=v"(r) : "v"(a), "v"(b));
  return r;
}

// ---------------------------------------------------------------------------
// prep (grid-fused): blocks x<72 transpose x fp32 [b][256][2304] ->
// xT bf16 [b][2304][256]; blocks x==72 convert w_qkv+w_out fp32->bf16.
// ---------------------------------------------------------------------------
__global__ __launch_bounds__(256) void prep_fused(
    const float* __restrict__ x, const float* __restrict__ wq,
    const float* __restrict__ wo, u16* __restrict__ xT,
    u16* __restrict__ wbf) {
  const int t = threadIdx.x;
  if (blockIdx.x == 72) {  // weight conversion: 32 blocks x 256 thr x 32 elems
    const int cid = blockIdx.y * 4 + blockIdx.z;  // 0..31
    const int base = cid * 8192;
#pragma unroll
    for (int i = 0; i < 8; ++i) {
      int idx = base + (i * 256 + t) * 4;
      float4 v;
      if (idx < 196608) v = *(const float4*)(wq + idx);
      else              v = *(const float4*)(wo + (idx - 196608));
      u16x4 p = {f2bf(v.x), f2bf(v.y), f2bf(v.z), f2bf(v.w)};
      *(u16x4*)(wbf + idx) = p;
    }
    return;
  }
  __shared__ float tile[32][33];
  const int n0 = blockIdx.x * 32, c0 = blockIdx.y * 32, b = blockIdx.z;
  const float* xb = x + ((size_t)b * 256 + c0) * NSP + n0;
#pragma unroll
  for (int e = t; e < 1024; e += 256) {
    int cc = e >> 5, nn = e & 31;
    tile[cc][nn] = xb[(size_t)cc * NSP + nn];
  }
  __syncthreads();
  u16* xTb = xT + ((size_t)b * NSP + n0) * 256 + c0;
#pragma unroll
  for (int e = t; e < 1024; e += 256) {
    int nn = e >> 5, cc = e & 31;
    xTb[(size_t)nn * 256 + cc] = f2bf(tile[cc][nn]);
  }
}

// ---------------------------------------------------------------------------
// bf16 MFMA GEMM (LDS-staged): D = A (Mx256) * B[b](Nx256)^T
// 64x64 tile, 4 waves (2x2 of 32x32), whole K=256 staged once.
// EPI 0: rows <256 q (pre-scaled K1S), 256..511 k -> qkT[b][n][512] bf16;
//        rows >=512 v -> vbuf[b][256][2304] bf16.
// EPI 1: fp32 out + bias.
// ---------------------------------------------------------------------------
template <int EPI>
__global__ __launch_bounds__(256) void gemm_mfma(
    const u16* __restrict__ A, const u16* __restrict__ B,
    u16* __restrict__ qkT, u16* __restrict__ vbuf,
    float* __restrict__ outf, const float* __restrict__ bias, int N) {
  __shared__ u16 As[64][264];
  __shared__ u16 Bs[64][264];
  const int t = threadIdx.x, lane = t & 63, wid = t >> 6;
  const int lo = lane & 15, g = lane >> 4;
  const int wr = wid >> 1, wc = wid & 1;
  const int row0 = blockIdx.y * 64, col0 = blockIdx.x * 64, b = blockIdx.z;

  const int sr = t >> 2, c4 = t & 3;
  const u16* Arow = A + (size_t)(row0 + sr) * 256;
  const u16* Brow = B + ((size_t)b * N + col0 + sr) * 256;
#pragma unroll
  for (int i = 0; i < 8; ++i) {
    int col = (c4 + 4 * i) * 8;
    *(uint4*)&As[sr][col] = *(const uint4*)&Arow[col];
    *(uint4*)&Bs[sr][col] = *(const uint4*)&Brow[col];
  }
  __syncthreads();

  f32x4 acc[2][2];
#pragma unroll
  for (int i = 0; i < 2; ++i)
#pragma unroll
    for (int j = 0; j < 2; ++j) acc[i][j] = (f32x4){0, 0, 0, 0};

  const int ar0 = wr * 32 + lo, br0 = wc * 32 + lo;
#pragma unroll
  for (int kk = 0; kk < 8; ++kk) {
    int kc = kk * 32 + g * 8;
    short8 a0 = *(const short8*)&As[ar0][kc];
    short8 a1 = *(const short8*)&As[ar0 + 16][kc];
    short8 b0 = *(const short8*)&Bs[br0][kc];
    short8 b1 = *(const short8*)&Bs[br0 + 16][kc];
    acc[0][0] = __builtin_amdgcn_mfma_f32_16x16x32_bf16(a0, b0, acc[0][0], 0, 0, 0);
    acc[0][1] = __builtin_amdgcn_mfma_f32_16x16x32_bf16(a0, b1, acc[0][1], 0, 0, 0);
    acc[1][0] = __builtin_amdgcn_mfma_f32_16x16x32_bf16(a1, b0, acc[1][0], 0, 0, 0);
    acc[1][1] = __builtin_amdgcn_mfma_f32_16x16x32_bf16(a1, b1, acc[1][1], 0, 0, 0);
  }

  const float qs = (EPI == 0 && row0 < 256) ? K1S : 1.0f;
#pragma unroll
  for (int m2 = 0; m2 < 2; ++m2)
#pragma unroll
    for (int n2 = 0; n2 < 2; ++n2) {
      int m = row0 + wr * 32 + m2 * 16 + g * 4;
      int n = col0 + wc * 32 + n2 * 16 + lo;
      if constexpr (EPI == 0) {
        if (row0 < 512) {  // q,k -> transposed qkT[b][n][m..m+3]
          u16x4 pk = {f2bf(acc[m2][n2][0] * qs), f2bf(acc[m2][n2][1] * qs),
                      f2bf(acc[m2][n2][2] * qs), f2bf(acc[m2][n2][3] * qs)};
          *(u16x4*)(qkT + ((size_t)b * NSP + n) * 512 + m) = pk;
        } else {           // v -> natural vbuf[b][m-512][n]
#pragma unroll
          for (int r = 0; r < 4; ++r)
            vbuf[((size_t)b * 256 + (m - 512 + r)) * NSP + n] =
                f2bf(acc[m2][n2][r]);
        }
      } else {
#pragma unroll
        for (int r = 0; r < 4; ++r)
          outf[((size_t)b * 256 + m + r) * NSP + n] =
              acc[m2][n2][r] + bias[m + r];
      }
    }
}

// ---------------------------------------------------------------------------
// MFMA flash attention, KEY-SPLIT 4-wave blocks (256 thr).
// Block = 64 queries (it tile). Wave w: wq = w&1 (32 q, 2 Q-frags),
// par = w>>1 (key half). Both parities share the same double-buffered 64-key
// strip (r9 pipeline, 1 barrier/strip); parity par computes keys
// [32par, 32par+32) of each strip. 4608 waves total = 18 waves/CU.
// P in-register (sigma trick, cvt_pk packing); Kt[64][40] / Vs[32][68]
// (r9-verified layouts); row-sum l via ones-MFMA; no-max exp2 softmax =>
// parity merge is a plain add through reused LDS (union).
// XCD swizzle: h = blockIdx%8 keeps each (b,h)'s K/V on one XCD's L2.
// ---------------------------------------------------------------------------
__global__ __launch_bounds__(256, 4) void attn_mfma(
    const u16* __restrict__ qkT, const u16* __restrict__ vbuf,
    u16* __restrict__ attnoT) {
  const int jb = blockIdx.x;
  const int h = jb & 7;
  const int qq = jb >> 3;
  const int it = qq % 36;
  const int b  = qq / 36;
  const int t = threadIdx.x, lane = t & 63, w = t >> 6;
  const int wq = w & 1, par = w >> 1;
  const int lo = lane & 15, g = lane >> 4;
  const int i0 = it * 64;
  const int poff = par * 32;

  const u16* qkTb = qkT + (size_t)b * NSP * 512;
  const u16* vb   = vbuf + ((size_t)b * 256 + h * 32) * NSP;
  u16* ob = attnoT + ((size_t)b * NSP + i0) * 256 + h * 32;

  __shared__ union SU {
    struct { u16 Kt[2][64][40]; u16 Vs[2][32][68]; } s;  // 18944 B
    float mrg[2][2][64][12];                             // 12288 B (epilogue)
  } u;

  // two Q fragments: queries i0 + wq*32 + qh*16 + lo (pre-scaled by K1S)
  short8 qf[2];
#pragma unroll
  for (int qh = 0; qh < 2; ++qh)
    qf[qh] = *(const short8*)(qkTb +
              (size_t)(i0 + wq * 32 + qh * 16 + lo) * 512 + h * 32 + g * 8);

  // staging (256 thr, 64-key strips): K one b128/thread, V one b128/thread
  const int kr = t >> 2, kp = (t & 3) * 8;   // K: row j (64), d-part
  const int vr = t >> 3, vp = (t & 7) * 8;   // V: row d (32), j-part
  const u16* ksrc = qkTb + 256 + h * 32 + kp;           // + j*512
  const u16* vsrc = vb + (size_t)vr * NSP + vp;         // + j0

  uint4 k0 = *(const uint4*)(ksrc + (size_t)kr * 512);
  uint4 v0 = *(const uint4*)(vsrc);
  *(uint4*)&u.s.Kt[0][kr][kp] = k0;
  *(uint4*)&u.s.Vs[0][vr][vp] = v0;
  __syncthreads();

  short8 ones;
#pragma unroll
  for (int e = 0; e < 8; ++e) ones[e] = (short)0x3F80;  // bf16 1.0

  f32x4 a0[2], a1[2], al[2];
#pragma unroll
  for (int qh = 0; qh < 2; ++qh) {
    a0[qh] = (f32x4){0, 0, 0, 0};
    a1[qh] = (f32x4){0, 0, 0, 0};
    al[qh] = (f32x4){0, 0, 0, 0};
  }

  for (int s = 0; s < 36; ++s) {
    const int cur = s & 1;
    if (s + 1 < 36) {  // prefetch next strip into regs (hidden under compute)
      int j0n = (s + 1) * 64;
      k0 = *(const uint4*)(ksrc + (size_t)(j0n + kr) * 512);
      v0 = *(const uint4*)(vsrc + j0n);
    }

    // ---- this parity's K fragments (keys poff..poff+31) ----
    short8 kf0 = *(const short8*)&u.s.Kt[cur][poff + lo][g * 8];
    short8 kf1 = *(const short8*)&u.s.Kt[cur][poff + 16 + lo][g * 8];
    // ---- V fragments under sigma: b64 pairs at j = poff+{4g, 16+4g} ----
    short4v v0a = *(const short4v*)&u.s.Vs[cur][lo][poff + 4 * g];
    short4v v0b = *(const short4v*)&u.s.Vs[cur][lo][poff + 16 + 4 * g];
    short4v v1a = *(const short4v*)&u.s.Vs[cur][16 + lo][poff + 4 * g];
    short4v v1b = *(const short4v*)&u.s.Vs[cur][16 + lo][poff + 16 + 4 * g];
    short8 vf0 = __builtin_shufflevector(v0a, v0b, 0, 1, 2, 3, 4, 5, 6, 7);
    short8 vf1 = __builtin_shufflevector(v1a, v1b, 0, 1, 2, 3, 4, 5, 6, 7);

#pragma unroll
    for (int qh = 0; qh < 2; ++qh) {
      __builtin_amdgcn_s_setprio(1);
      f32x4 sv0 = __builtin_amdgcn_mfma_f32_16x16x32_bf16(
          kf0, qf[qh], (f32x4){0, 0, 0, 0}, 0, 0, 0);
      f32x4 sv1 = __builtin_amdgcn_mfma_f32_16x16x32_bf16(
          kf1, qf[qh], (f32x4){0, 0, 0, 0}, 0, 0, 0);
      __builtin_amdgcn_s_setprio(0);

      f32x4 e0, e1;
#pragma unroll
      for (int r = 0; r < 4; ++r) {
        e0[r] = __builtin_amdgcn_exp2f(sv0[r]);
        e1[r] = __builtin_amdgcn_exp2f(sv1[r]);
      }
      uint4 P = {cvtpk(e0[0], e0[1]), cvtpk(e0[2], e0[3]),
                 cvtpk(e1[0], e1[1]), cvtpk(e1[2], e1[3])};
      short8 pf = __builtin_bit_cast(short8, P);

      __builtin_amdgcn_s_setprio(1);
      a0[qh] = __builtin_amdgcn_mfma_f32_16x16x32_bf16(pf, vf0, a0[qh], 0, 0, 0);
      a1[qh] = __builtin_amdgcn_mfma_f32_16x16x32_bf16(pf, vf1, a1[qh], 0, 0, 0);
      al[qh] = __builtin_amdgcn_mfma_f32_16x16x32_bf16(pf, ones, al[qh], 0, 0, 0);
      __builtin_amdgcn_s_setprio(0);
    }

    if (s + 1 < 36) {  // write next strip into the other buffer
      *(uint4*)&u.s.Kt[cur ^ 1][kr][kp] = k0;
      *(uint4*)&u.s.Vs[cur ^ 1][vr][vp] = v0;
    }
    __syncthreads();
  }

  // ---- parity merge (accumulators add: shared exp2 offset), then store ----
  if (par == 1) {
#pragma unroll
    for (int qh = 0; qh < 2; ++qh) {
      *(f32x4*)&u.mrg[wq][qh][lane][0] = a0[qh];
      *(f32x4*)&u.mrg[wq][qh][lane][4] = a1[qh];
      *(f32x4*)&u.mrg[wq][qh][lane][8] = al[qh];
    }
  }
  __syncthreads();
  if (par == 0) {
#pragma unroll
    for (int qh = 0; qh < 2; ++qh) {
      f32x4 m0 = *(const f32x4*)&u.mrg[wq][qh][lane][0];
      f32x4 m1 = *(const f32x4*)&u.mrg[wq][qh][lane][4];
      f32x4 ml = *(const f32x4*)&u.mrg[wq][qh][lane][8];
#pragma unroll
      for (int r = 0; r < 4; ++r) {
        float inv = 1.0f / (al[qh][r] + ml[r]);
        int row = wq * 32 + qh * 16 + g * 4 + r;
        ob[(size_t)row * 256 + lo]      = f2bf((a0[qh][r] + m0[r]) * inv);
        ob[(size_t)row * 256 + 16 + lo] = f2bf((a1[qh][r] + m1[r]) * inv);
      }
    }
  }
}

// ---------------------------------------------------------------------------
extern "C" void kernel_launch(void* const* d_in, const int* in_sizes, int n_in,
                              void* d_out, int out_size, void* d_ws, size_t ws_size,
                              hipStream_t stream) {
  const float* x     = (const float*)d_in[0];  // [4][256][48][48]
  const float* w_qkv = (const float*)d_in[1];  // [768][256]
  const float* w_out = (const float*)d_in[2];  // [256][256]
  const float* b_out = (const float*)d_in[3];  // [256]
  float* out = (float*)d_out;                  // [4][256][2304]

  u16* wbf    = (u16*)d_ws;                    // wqkv 196608 then wout 65536
  u16* xT     = wbf + 262144;                  // [4][2304][256]
  u16* qkT    = xT + (size_t)NB * NSP * 256;   // [4][2304][512]
  u16* vbuf   = qkT + (size_t)NB * NSP * 512;  // [4][256][2304]
  u16* attnoT = vbuf + (size_t)NB * 256 * NSP; // [4][2304][256]

  dim3 blk(256);
  prep_fused<<<dim3(73, 8, NB), blk, 0, stream>>>(x, w_qkv, w_out, xT, wbf);
  gemm_mfma<0><<<dim3(NSP / 64, 12, NB), blk, 0, stream>>>(
      wbf, xT, qkT, vbuf, nullptr, nullptr, NSP);
  attn_mfma<<<dim3(1152), blk, 0, stream>>>(qkT, vbuf, attnoT);
  gemm_mfma<1><<<dim3(NSP / 64, 4, NB), blk, 0, stream>>>(
      wbf + 196608, attnoT, nullptr, nullptr, out, b_out, NSP);
}